// Round 7
// baseline (773.079 us; speedup 1.0000x reference)
//
#include <hip/hip_runtime.h>
#include <hip/hip_bf16.h>
#include <stdint.h>

// Problem dims (B=2, T=2048, H=1024, F=4096, E=8)
#define BT   4096
#define HDIM 1024
#define FDIM 4096
#define EDIM 8
#define TOPP 0.8f
#define KCAT (EDIM * FDIM)   // 32768 concatenated K for GEMM2

typedef unsigned short u16;
typedef __attribute__((ext_vector_type(8))) short  short8;
typedef __attribute__((ext_vector_type(8))) unsigned short ushort8;
typedef __attribute__((ext_vector_type(4))) float  f32x4;

// ---------- helpers ----------
__device__ __forceinline__ u16 f2bf(float f) {
  uint32_t u = __builtin_bit_cast(uint32_t, f);
  uint32_t r = u + 0x7FFFu + ((u >> 16) & 1u);   // RNE
  return (u16)(r >> 16);
}

__device__ __forceinline__ void gload_lds16(const void* g, void* l) {
  __builtin_amdgcn_global_load_lds(
      (const __attribute__((address_space(1))) uint32_t*)g,
      (__attribute__((address_space(3))) uint32_t*)l, 16, 0, 0);
}

#define VMWAIT2() asm volatile("s_waitcnt vmcnt(2)" ::: "memory")
#define VMWAIT0() asm volatile("s_waitcnt vmcnt(0)" ::: "memory")
#define BAR()     asm volatile("s_barrier" ::: "memory")
#define SB()      __builtin_amdgcn_sched_barrier(0)

// Bijective XCD-aware swizzle (m204)
__device__ __forceinline__ int xcd_swizzle(int bid, int nwg) {
  const int nx = 8;
  int q = nwg / nx, r = nwg % nx;
  int xcd = bid % nx, lin = bid / nx;
  int base = (xcd < r) ? xcd * (q + 1) : r * (q + 1) + (xcd - r) * q;
  return base + lin;
}

// ---------- router: probs -> top-p gate (stable argsort semantics) ----------
__global__ __launch_bounds__(256) void router_kernel(
    const float* __restrict__ x, const float* __restrict__ Wr,
    const float* __restrict__ br, float* __restrict__ gate) {
  const int wid  = threadIdx.x >> 6;
  const int lane = threadIdx.x & 63;
  const int token = blockIdx.x * 4 + wid;
  const float* xr = x + (size_t)token * HDIM;

  float p[8] = {0.f,0.f,0.f,0.f,0.f,0.f,0.f,0.f};
  #pragma unroll
  for (int j = 0; j < 16; ++j) {
    int hh = lane * 16 + j;
    float xv = xr[hh];
    const float* wrow = Wr + (size_t)hh * 8;
    #pragma unroll
    for (int e = 0; e < 8; ++e) p[e] += xv * wrow[e];
  }
  #pragma unroll
  for (int off = 32; off > 0; off >>= 1) {
    #pragma unroll
    for (int e = 0; e < 8; ++e) p[e] += __shfl_xor(p[e], off, 64);
  }
  float mx = -1e30f;
  #pragma unroll
  for (int e = 0; e < 8; ++e) { p[e] += br[e]; mx = fmaxf(mx, p[e]); }
  float s = 0.f;
  #pragma unroll
  for (int e = 0; e < 8; ++e) { p[e] = expf(p[e] - mx); s += p[e]; }
  float inv = 1.0f / s;
  #pragma unroll
  for (int e = 0; e < 8; ++e) p[e] *= inv;

  if (lane == 0) {
    float g[8];
    #pragma unroll
    for (int e = 0; e < 8; ++e) {
      float pe = p[e];
      float cum = pe; int rank = 0;
      #pragma unroll
      for (int e2 = 0; e2 < 8; ++e2) {
        if (e2 == e) continue;
        bool before = (p[e2] > pe) || (p[e2] == pe && e2 < e);
        if (before) { cum += p[e2]; rank++; }
      }
      bool keep = (cum < TOPP) || (rank == 0);
      g[e] = keep ? pe : 0.f;
    }
    float* gp = gate + (size_t)token * 8;
    #pragma unroll
    for (int e = 0; e < 8; ++e) gp[e] = g[e];
  }
}

// ---------- cast x f32 -> bf16 ----------
__global__ __launch_bounds__(256) void cast_x_kernel(
    const float* __restrict__ in, u16* __restrict__ out) {
  int i = (blockIdx.x * 256 + threadIdx.x) * 8;
  float4 a = *(const float4*)(in + i);
  float4 b = *(const float4*)(in + i + 4);
  ushort8 o;
  o[0] = f2bf(a.x); o[1] = f2bf(a.y); o[2] = f2bf(a.z); o[3] = f2bf(a.w);
  o[4] = f2bf(b.x); o[5] = f2bf(b.y); o[6] = f2bf(b.z); o[7] = f2bf(b.w);
  *(ushort8*)(out + i) = o;
}

// ---------- transpose + cast: per-expert (R,C) f32 -> out[e*estride + c*rstride + r] bf16
__global__ __launch_bounds__(256) void transpose_cast_kernel(
    const float* __restrict__ in, u16* __restrict__ out, int R, int C,
    size_t rstride, size_t estride) {
  __shared__ float tile[32][33];
  const int e = blockIdx.z;
  const float* ip = in + (size_t)e * R * C;
  u16* op = out + (size_t)e * estride;
  int x  = blockIdx.x * 32 + threadIdx.x;   // C coord
  int y0 = blockIdx.y * 32;                 // R tile base
  int ty = threadIdx.y;                     // 0..7
  #pragma unroll
  for (int j = 0; j < 32; j += 8)
    tile[ty + j][threadIdx.x] = ip[(size_t)(y0 + ty + j) * C + x];
  __syncthreads();
  int xo  = y0 + threadIdx.x;               // R coord (contiguous on out)
  int yo0 = blockIdx.x * 32;
  #pragma unroll
  for (int j = 0; j < 32; j += 8)
    op[(size_t)(yo0 + ty + j) * rstride + xo] = f2bf(tile[threadIdx.x][ty + j]);
}

// ======================================================================
// 256x256-tile GEMM, BK=64, 8 waves (2M x 4N, wave-tile 128x64),
// quadrant phases + ONE-PHASE REGISTER READ-AHEAD: ds_reads for phase
// p issued during phase p-1's MFMA, so LDS delivery overlaps the matrix
// pipe. Stage/gate: one half-tile per p1/p2, two at p3, vmcnt(2) gate at
// p3 (leaves only A-lo(u+2) in flight), next-tile reads issued only
// after the gate's barrier (cross-wave publication).
// MODE 0 (GEMM1): h_all[row, e*F+col] = bf16(gate*relu(x@W1_e + b1))
// MODE 1 (GEMM2): part[z] = A'(BT,KCAT) x B'^T  (K-split z, f32)
// ======================================================================
template <int MODE>
__global__ __launch_bounds__(512, 2) void gemm256(
    const u16* __restrict__ A0, const u16* __restrict__ B0,
    const float* __restrict__ bias, const float* __restrict__ gate,
    u16* __restrict__ hout, float* __restrict__ part) {
  // LDS bytes: A[p][row][gran]: p*32768 + row*128 + gran*16   (0..65535)
  //            B[p][row][gran]: 65536 + p*32768 + row*128 + gran*16
  __shared__ u16 lds[65536];   // 128 KiB

  constexpr int NXT  = (MODE == 0 ? 16 : 4);
  constexpr int NYT  = 16;
  constexpr int NZ   = (MODE == 0 ? 8 : 4);
  constexpr int NT   = (MODE == 0 ? HDIM / 64 : (KCAT / NZ) / 64);  // 16 / 128
  constexpr size_t Kstr = (MODE == 0 ? (size_t)HDIM : (size_t)KCAT);

  const int tid  = threadIdx.x;
  const int wid  = tid >> 6;
  const int lane = tid & 63;

  int lin = (blockIdx.z * gridDim.y + blockIdx.y) * gridDim.x + blockIdx.x;
  lin = xcd_swizzle(lin, NXT * NYT * NZ);
  const int bn = lin % NXT; lin /= NXT;
  const int bm = lin % NYT; lin /= NYT;
  const int bz = lin;                       // expert (MODE0) or k-split (MODE1)

  const u16* Abase = A0 + (size_t)bm * 256 * Kstr
                        + (MODE == 0 ? 0 : (size_t)bz * (KCAT / NZ));
  const u16* Bbase = (MODE == 0 ? B0 + (size_t)bz * FDIM * HDIM
                                : B0 + (size_t)bz * (KCAT / NZ))
                        + (size_t)bn * 256 * Kstr;

  // ---- staging geometry (hoisted): thread covers (row=tid>>3 [+64], granule=tid&7)
  const int srow = tid >> 3;                         // 0..63
  const int sg   = tid & 7;                          // dest granule
  const int scol = (sg ^ (srow & 7)) * 8;            // pre-swizzled src col (u16)
  const u16* gA = Abase + (size_t)srow * Kstr + scol;   // A-lo row base
  const u16* gB = Bbase + (size_t)srow * Kstr + scol;   // B-lo row base
  char* const ldsT = (char*)lds + tid * 16;

  // STAGEH(T, WH): stage half-tile WH (0=A-lo,1=A-hi,2=B-lo,3=B-hi) of K-tile T
  #define STAGEH(T, WH) do {                                              \
    const u16* _s = ((WH) < 2 ? gA : gB)                                  \
                    + (size_t)(((WH) & 1) * 128) * Kstr + (size_t)(T) * 64;\
    char* _d = ldsT + ((WH) >= 2 ? 65536 : 0) + ((T) & 1) * 32768         \
               + ((WH) & 1) * 16384;                                      \
    gload_lds16(_s, _d);                                                  \
    gload_lds16(_s + 64 * Kstr, _d + 8192);                               \
  } while (0)

  const int wm = wid >> 2, wn = wid & 3;   // 2M x 4N waves, each 128x64
  const int l4 = lane >> 4, l15 = lane & 15;

  f32x4 acc[8][4];
  #pragma unroll
  for (int i = 0; i < 8; ++i)
    #pragma unroll
    for (int j = 0; j < 4; ++j) acc[i][j] = {0.f, 0.f, 0.f, 0.f};

  // swizzled LDS read byte-offsets: [mi][kk], [ni][kk]
  int aof[8][2], bof[4][2];
  #pragma unroll
  for (int mi = 0; mi < 8; ++mi) {
    int row = wm * 128 + mi * 16 + l15;
    aof[mi][0] = row * 128 + ((l4       ^ (row & 7)) * 16);
    aof[mi][1] = row * 128 + (((4 + l4) ^ (row & 7)) * 16);
  }
  #pragma unroll
  for (int ni = 0; ni < 4; ++ni) {
    int row = wn * 64 + ni * 16 + l15;
    bof[ni][0] = 65536 + row * 128 + ((l4       ^ (row & 7)) * 16);
    bof[ni][1] = 65536 + row * 128 + (((4 + l4) ^ (row & 7)) * 16);
  }

  #define LD(off) (*(const short8*)((const char*)lds + (off)))

  short8 a_[8][2], b_[4][2];
  #define RD_A03(P) do { _Pragma("unroll")                                \
    for (int i = 0; i < 4; ++i) {                                         \
      a_[i][0] = LD((P) + aof[i][0]); a_[i][1] = LD((P) + aof[i][1]); } } while (0)
  #define RD_A47(P) do { _Pragma("unroll")                                \
    for (int i = 4; i < 8; ++i) {                                         \
      a_[i][0] = LD((P) + aof[i][0]); a_[i][1] = LD((P) + aof[i][1]); } } while (0)
  #define RD_B01(P) do {                                                  \
    b_[0][0] = LD((P) + bof[0][0]); b_[0][1] = LD((P) + bof[0][1]);       \
    b_[1][0] = LD((P) + bof[1][0]); b_[1][1] = LD((P) + bof[1][1]); } while (0)
  #define RD_B23(P) do {                                                  \
    b_[2][0] = LD((P) + bof[2][0]); b_[2][1] = LD((P) + bof[2][1]);       \
    b_[3][0] = LD((P) + bof[3][0]); b_[3][1] = LD((P) + bof[3][1]); } while (0)

  // 16-MFMA quadrant: mi in [M0,M0+4) x ni in [N0,N0+2) x kk 0,1
  #define QUAD(M0, N0) do {                                               \
    __builtin_amdgcn_s_setprio(1);                                        \
    _Pragma("unroll")                                                     \
    for (int i = 0; i < 4; ++i) {                                         \
      acc[(M0) + i][N0]     = __builtin_amdgcn_mfma_f32_16x16x32_bf16(    \
          a_[(M0) + i][0], b_[N0][0],     acc[(M0) + i][N0],     0, 0, 0);\
      acc[(M0) + i][N0]     = __builtin_amdgcn_mfma_f32_16x16x32_bf16(    \
          a_[(M0) + i][1], b_[N0][1],     acc[(M0) + i][N0],     0, 0, 0);\
      acc[(M0) + i][(N0)+1] = __builtin_amdgcn_mfma_f32_16x16x32_bf16(    \
          a_[(M0) + i][0], b_[(N0)+1][0], acc[(M0) + i][(N0)+1], 0, 0, 0);\
      acc[(M0) + i][(N0)+1] = __builtin_amdgcn_mfma_f32_16x16x32_bf16(    \
          a_[(M0) + i][1], b_[(N0)+1][1], acc[(M0) + i][(N0)+1], 0, 0, 0);\
    }                                                                     \
    __builtin_amdgcn_s_setprio(0);                                        \
  } while (0)

  // ---- prologue: tile 0 + A-lo(1); gate; issue Q1(0)'s reads ----
  STAGEH(0, 0); STAGEH(0, 1); STAGEH(0, 2); STAGEH(0, 3);
  STAGEH(1, 0);
  VMWAIT2();    // 10 outstanding -> <=2: tile 0 landed (A-lo(1) in flight)
  BAR();
  RD_A03(0); RD_B01(0);   // 12 reads for Q1(0), published by the BAR above

  for (int u = 0; u < NT; ++u) {
    const int pA = (u & 1) * 32768;   // this tile's buffer (byte offset)
    const int pN = pA ^ 32768;        // next tile's buffer

    // -- p1: read b23(u) [for Q2]; stage A-hi(u+1); MFMA Q1(u) --
    RD_B23(pA);
    if (u + 1 < NT) STAGEH(u + 1, 1);
    BAR(); SB();
    QUAD(0, 0);
    SB(); BAR();

    // -- p2: read a47(u) [for Q3]; stage B-lo(u+1); MFMA Q2(u) --
    RD_A47(pA);
    if (u + 1 < NT) STAGEH(u + 1, 2);
    BAR(); SB();
    QUAD(0, 2);
    SB(); BAR();

    // -- p3: stage B-hi(u+1)+A-lo(u+2); gate; read a03(u+1); MFMA Q3(u) --
    if (u + 1 < NT) STAGEH(u + 1, 3);
    if (u + 2 < NT) STAGEH(u + 2, 0);
    if (u + 2 < NT) { VMWAIT2(); } else if (u + 1 < NT) { VMWAIT0(); }
    BAR();
    if (u + 1 < NT) RD_A03(pN);   // tile u+1 fully published by gate+BAR
    SB();
    QUAD(4, 0);
    SB(); BAR();

    // -- p4: read b01(u+1) [for Q1(u+1)]; MFMA Q4(u) --
    if (u + 1 < NT) RD_B01(pN);
    BAR(); SB();
    QUAD(4, 2);
    SB(); BAR();
  }

  // ---------------- epilogue ----------------
  const int rowbase = bm * 256 + wm * 128;
  const int colbase = bn * 256 + wn * 64;

  if constexpr (MODE == 0) {
    float bv[4];
    #pragma unroll
    for (int ni = 0; ni < 4; ++ni)
      bv[ni] = bias[(size_t)bz * FDIM + colbase + ni * 16 + l15];
    #pragma unroll
    for (int mi = 0; mi < 8; ++mi) {
      #pragma unroll
      for (int r = 0; r < 4; ++r) {
        const int row = rowbase + mi * 16 + l4 * 4 + r;
        const float gv = gate[(size_t)row * 8 + bz];
        #pragma unroll
        for (int ni = 0; ni < 4; ++ni) {
          const int col = colbase + ni * 16 + l15;
          float v = fmaxf(acc[mi][ni][r] + bv[ni], 0.f);
          hout[(size_t)row * KCAT + (size_t)bz * FDIM + col] = f2bf(gv * v);
        }
      }
    }
  } else {
    float* pp = part + (size_t)bz * BT * HDIM;
    #pragma unroll
    for (int mi = 0; mi < 8; ++mi) {
      #pragma unroll
      for (int r = 0; r < 4; ++r) {
        const int row = rowbase + mi * 16 + l4 * 4 + r;
        #pragma unroll
        for (int ni = 0; ni < 4; ++ni) {
          const int col = colbase + ni * 16 + l15;
          pp[(size_t)row * HDIM + col] = acc[mi][ni][r];
        }
      }
    }
  }
  #undef STAGEH
  #undef LD
  #undef RD_A03
  #undef RD_A47
  #undef RD_B01
  #undef RD_B23
  #undef QUAD
}

// ---------- reduce: out = sum_z part[z] + sum_e gate[row][e]*b2[e][col] ----------
__global__ __launch_bounds__(256) void reduce_kernel(
    const float* __restrict__ part, const float* __restrict__ gate,
    const float* __restrict__ b2, float* __restrict__ out) {
  const int i = (blockIdx.x * 256 + threadIdx.x) * 4;
  const int row = i >> 10, col = i & 1023;
  float4 s = *(const float4*)(part + i);
  #pragma unroll
  for (int z = 1; z < 4; ++z) {
    float4 t = *(const float4*)(part + (size_t)z * BT * HDIM + i);
    s.x += t.x; s.y += t.y; s.z += t.z; s.w += t.w;
  }
  const float* g = gate + (size_t)row * 8;
  #pragma unroll
  for (int e = 0; e < 8; ++e) {
    float ge = g[e];
    float4 bv = *(const float4*)(b2 + (size_t)e * HDIM + col);
    s.x += ge * bv.x; s.y += ge * bv.y; s.z += ge * bv.z; s.w += ge * bv.w;
  }
  *(float4*)(out + i) = s;
}

// ======================================================================
// Fallback (R2-proven): 128x128-tile per-expert GEMMs, used if ws too small
// ======================================================================
template <int Ndim, int Kdim, int EPI>
__global__ __launch_bounds__(256) void gemm_fb(
    const u16* __restrict__ A, const u16* __restrict__ Bt,
    const float* __restrict__ bias, const float* __restrict__ gate,
    int expert, u16* __restrict__ Hout, float* __restrict__ Cout) {
  __shared__ u16 Atile[128 * 32];
  __shared__ u16 Btile[128 * 32];
  const int tid  = threadIdx.x;
  const int wid  = tid >> 6;
  const int lane = tid & 63;
  const int NXT = Ndim / 128;
  const int nwg = gridDim.x * gridDim.y;
  const int bid = xcd_swizzle(blockIdx.y * gridDim.x + blockIdx.x, nwg);
  const int bn = bid % NXT, bm = bid / NXT;
  const int wm = wid >> 1, wn = wid & 1;
  const int l4  = lane >> 4, l15 = lane & 15;
  f32x4 acc[4][4];
  #pragma unroll
  for (int i = 0; i < 4; ++i)
    #pragma unroll
    for (int j = 0; j < 4; ++j) acc[i][j] = {0.f, 0.f, 0.f, 0.f};
  const int srow = lane >> 2;
  const int scol = (lane & 3) * 8;
  for (int k0 = 0; k0 < Kdim; k0 += 32) {
    __syncthreads();
    #pragma unroll
    for (int i = 0; i < 2; ++i) {
      int c = wid * 2 + i;
      gload_lds16(A  + (size_t)(bm * 128 + c * 16 + srow) * Kdim + k0 + scol, &Atile[c * 512]);
      gload_lds16(Bt + (size_t)(bn * 128 + c * 16 + srow) * Kdim + k0 + scol, &Btile[c * 512]);
    }
    __syncthreads();
    short8 af[4], bf[4];
    #pragma unroll
    for (int mi = 0; mi < 4; ++mi)
      af[mi] = *(const short8*)&Atile[(wm * 64 + mi * 16 + l15) * 32 + l4 * 8];
    #pragma unroll
    for (int ni = 0; ni < 4; ++ni)
      bf[ni] = *(const short8*)&Btile[(wn * 64 + ni * 16 + l15) * 32 + l4 * 8];
    #pragma unroll
    for (int mi = 0; mi < 4; ++mi)
      #pragma unroll
      for (int ni = 0; ni < 4; ++ni)
        acc[mi][ni] = __builtin_amdgcn_mfma_f32_16x16x32_bf16(af[mi], bf[ni], acc[mi][ni], 0, 0, 0);
  }
  const int cm0 = bm * 128 + wm * 64;
  const int cn0 = bn * 128 + wn * 64;
  float bv[4];
  #pragma unroll
  for (int ni = 0; ni < 4; ++ni) bv[ni] = bias[cn0 + ni * 16 + l15];
  #pragma unroll
  for (int mi = 0; mi < 4; ++mi) {
    #pragma unroll
    for (int r = 0; r < 4; ++r) {
      const int row = cm0 + mi * 16 + l4 * 4 + r;
      float gv = 0.f;
      if (EPI != 0) gv = gate[(size_t)row * 8 + expert];
      #pragma unroll
      for (int ni = 0; ni < 4; ++ni) {
        const int col = cn0 + ni * 16 + l15;
        float v = acc[mi][ni][r] + bv[ni];
        if (EPI == 0)      Hout[(size_t)row * Ndim + col] = f2bf(fmaxf(v, 0.f));
        else if (EPI == 1) Cout[(size_t)row * Ndim + col] = gv * v;
        else               Cout[(size_t)row * Ndim + col] += gv * v;
      }
    }
  }
}

// ---------- launch ----------
extern "C" void kernel_launch(void* const* d_in, const int* in_sizes, int n_in,
                              void* d_out, int out_size, void* d_ws, size_t ws_size,
                              hipStream_t stream) {
  const float* x  = (const float*)d_in[0];
  const float* Wr = (const float*)d_in[1];
  const float* br = (const float*)d_in[2];
  const float* W1 = (const float*)d_in[3];
  const float* b1 = (const float*)d_in[4];
  const float* W2 = (const float*)d_in[5];
  const float* b2 = (const float*)d_in[6];
  float* out = (float*)d_out;

  const size_t sz_gate = (size_t)BT * EDIM * 4;            // 128 KB
  const size_t sz_xb   = (size_t)BT * HDIM * 2;            // 8 MB
  const size_t sz_w1t  = (size_t)EDIM * FDIM * HDIM * 2;   // 64 MB
  const size_t sz_w2t  = (size_t)EDIM * HDIM * FDIM * 2;   // 64 MB
  const size_t sz_hall = (size_t)BT * KCAT * 2;            // 256 MB
  const size_t need_primary = sz_gate + sz_xb + sz_w1t + sz_w2t + sz_hall;

  char* p = (char*)d_ws;
  float* gate = (float*)p; p += sz_gate;
  u16* xb   = (u16*)p;     p += sz_xb;
  u16* w1t  = (u16*)p;     char* w1t_region = (char*)w1t; p += sz_w1t;
  u16* w2t  = (u16*)p;     p += sz_w2t;

  router_kernel<<<BT / 4, 256, 0, stream>>>(x, Wr, br, gate);
  cast_x_kernel<<<(BT * HDIM) / (256 * 8), 256, 0, stream>>>(x, xb);
  // W1 (E,H,F) -> w1t[e][f][h]  (rstride=H, estride=F*H)
  transpose_cast_kernel<<<dim3(FDIM / 32, HDIM / 32, EDIM), dim3(32, 8), 0, stream>>>(
      W1, w1t, HDIM, FDIM, HDIM, (size_t)FDIM * HDIM);

  if (ws_size >= need_primary) {
    u16* h_all = (u16*)p;                       // (BT, KCAT) bf16
    float* part = (float*)w1t_region;           // 4 x (BT,H) f32, aliases w1t after G1
    // W2 (E,F,H) -> B'[n][e*F+f]  (rstride=KCAT, estride=F)
    transpose_cast_kernel<<<dim3(HDIM / 32, FDIM / 32, EDIM), dim3(32, 8), 0, stream>>>(
        W2, w2t, FDIM, HDIM, KCAT, FDIM);
    // GEMM1: all experts, h_all[row, e*F+col] = bf16(gate*relu(x@W1_e + b1_e))
    gemm256<0><<<dim3(16, 16, 8), 512, 0, stream>>>(xb, w1t, b1, gate, h_all, nullptr);
    // GEMM2: (g.h) @ concat(W2), split-K x4 -> part
    gemm256<1><<<dim3(4, 16, 4), 512, 0, stream>>>(h_all, w2t, nullptr, nullptr, nullptr, part);
    // out = sum_z part + sum_e g_e * b2_e
    reduce_kernel<<<(BT * HDIM) / (256 * 4), 256, 0, stream>>>(part, gate, b2, out);
  } else {
    // -------- fallback: R2-proven path --------
    u16* h = (u16*)p;   // (BT, F) one expert, 32 MB
    transpose_cast_kernel<<<dim3(HDIM / 32, FDIM / 32, EDIM), dim3(32, 8), 0, stream>>>(
        W2, w2t, FDIM, HDIM, FDIM, (size_t)HDIM * FDIM);
    for (int e = 0; e < EDIM; ++e) {
      gemm_fb<FDIM, HDIM, 0><<<dim3(FDIM / 128, BT / 128), 256, 0, stream>>>(
          xb, w1t + (size_t)e * FDIM * HDIM, b1 + (size_t)e * FDIM, nullptr, 0, h, nullptr);
      if (e == 0)
        gemm_fb<HDIM, FDIM, 1><<<dim3(HDIM / 128, BT / 128), 256, 0, stream>>>(
            h, w2t + (size_t)e * HDIM * FDIM, b2 + (size_t)e * HDIM, gate, e, nullptr, out);
      else
        gemm_fb<HDIM, FDIM, 2><<<dim3(HDIM / 128, BT / 128), 256, 0, stream>>>(
            h, w2t + (size_t)e * HDIM * FDIM, b2 + (size_t)e * HDIM, gate, e, nullptr, out);
    }
  }
}

// Round 9
// 651.696 us; speedup vs baseline: 1.1863x; 1.1863x over previous
//
#include <hip/hip_runtime.h>
#include <hip/hip_bf16.h>
#include <stdint.h>

// Problem dims (B=2, T=2048, H=1024, F=4096, E=8)
#define BT   4096
#define HDIM 1024
#define FDIM 4096
#define EDIM 8
#define TOPP 0.8f
#define KCAT (EDIM * FDIM)   // 32768 concatenated K for GEMM2

typedef unsigned short u16;
typedef __attribute__((ext_vector_type(8))) short  short8;
typedef __attribute__((ext_vector_type(8))) unsigned short ushort8;
typedef __attribute__((ext_vector_type(4))) float  f32x4;

// ---------- helpers ----------
__device__ __forceinline__ u16 f2bf(float f) {
  uint32_t u = __builtin_bit_cast(uint32_t, f);
  uint32_t r = u + 0x7FFFu + ((u >> 16) & 1u);   // RNE
  return (u16)(r >> 16);
}

__device__ __forceinline__ void gload_lds16(const void* g, void* l) {
  __builtin_amdgcn_global_load_lds(
      (const __attribute__((address_space(1))) uint32_t*)g,
      (__attribute__((address_space(3))) uint32_t*)l, 16, 0, 0);
}

#define VMWAIT2() asm volatile("s_waitcnt vmcnt(2)" ::: "memory")
#define VMWAIT0() asm volatile("s_waitcnt vmcnt(0)" ::: "memory")
#define BAR()     asm volatile("s_barrier" ::: "memory")

// Bijective XCD-aware swizzle (m204)
__device__ __forceinline__ int xcd_swizzle(int bid, int nwg) {
  const int nx = 8;
  int q = nwg / nx, r = nwg % nx;
  int xcd = bid % nx, lin = bid / nx;
  int base = (xcd < r) ? xcd * (q + 1) : r * (q + 1) + (xcd - r) * q;
  return base + lin;
}

// ---------- router: probs -> top-p gate (stable argsort semantics) ----------
__global__ __launch_bounds__(256) void router_kernel(
    const float* __restrict__ x, const float* __restrict__ Wr,
    const float* __restrict__ br, float* __restrict__ gate) {
  const int wid  = threadIdx.x >> 6;
  const int lane = threadIdx.x & 63;
  const int token = blockIdx.x * 4 + wid;
  const float* xr = x + (size_t)token * HDIM;

  float p[8] = {0.f,0.f,0.f,0.f,0.f,0.f,0.f,0.f};
  #pragma unroll
  for (int j = 0; j < 16; ++j) {
    int hh = lane * 16 + j;
    float xv = xr[hh];
    const float* wrow = Wr + (size_t)hh * 8;
    #pragma unroll
    for (int e = 0; e < 8; ++e) p[e] += xv * wrow[e];
  }
  #pragma unroll
  for (int off = 32; off > 0; off >>= 1) {
    #pragma unroll
    for (int e = 0; e < 8; ++e) p[e] += __shfl_xor(p[e], off, 64);
  }
  float mx = -1e30f;
  #pragma unroll
  for (int e = 0; e < 8; ++e) { p[e] += br[e]; mx = fmaxf(mx, p[e]); }
  float s = 0.f;
  #pragma unroll
  for (int e = 0; e < 8; ++e) { p[e] = expf(p[e] - mx); s += p[e]; }
  float inv = 1.0f / s;
  #pragma unroll
  for (int e = 0; e < 8; ++e) p[e] *= inv;

  if (lane == 0) {
    float g[8];
    #pragma unroll
    for (int e = 0; e < 8; ++e) {
      float pe = p[e];
      float cum = pe; int rank = 0;
      #pragma unroll
      for (int e2 = 0; e2 < 8; ++e2) {
        if (e2 == e) continue;
        bool before = (p[e2] > pe) || (p[e2] == pe && e2 < e);
        if (before) { cum += p[e2]; rank++; }
      }
      bool keep = (cum < TOPP) || (rank == 0);
      g[e] = keep ? pe : 0.f;
    }
    float* gp = gate + (size_t)token * 8;
    #pragma unroll
    for (int e = 0; e < 8; ++e) gp[e] = g[e];
  }
}

// ---------- cast x f32 -> bf16 ----------
__global__ __launch_bounds__(256) void cast_x_kernel(
    const float* __restrict__ in, u16* __restrict__ out) {
  int i = (blockIdx.x * 256 + threadIdx.x) * 8;
  float4 a = *(const float4*)(in + i);
  float4 b = *(const float4*)(in + i + 4);
  ushort8 o;
  o[0] = f2bf(a.x); o[1] = f2bf(a.y); o[2] = f2bf(a.z); o[3] = f2bf(a.w);
  o[4] = f2bf(b.x); o[5] = f2bf(b.y); o[6] = f2bf(b.z); o[7] = f2bf(b.w);
  *(ushort8*)(out + i) = o;
}

// ---------- transpose + cast: per-expert (R,C) f32 -> out[e*estride + c*rstride + r] bf16
__global__ __launch_bounds__(256) void transpose_cast_kernel(
    const float* __restrict__ in, u16* __restrict__ out, int R, int C,
    size_t rstride, size_t estride) {
  __shared__ float tile[32][33];
  const int e = blockIdx.z;
  const float* ip = in + (size_t)e * R * C;
  u16* op = out + (size_t)e * estride;
  int x  = blockIdx.x * 32 + threadIdx.x;   // C coord
  int y0 = blockIdx.y * 32;                 // R tile base
  int ty = threadIdx.y;                     // 0..7
  #pragma unroll
  for (int j = 0; j < 32; j += 8)
    tile[ty + j][threadIdx.x] = ip[(size_t)(y0 + ty + j) * C + x];
  __syncthreads();
  int xo  = y0 + threadIdx.x;               // R coord (contiguous on out)
  int yo0 = blockIdx.x * 32;
  #pragma unroll
  for (int j = 0; j < 32; j += 8)
    op[(size_t)(yo0 + ty + j) * rstride + xo] = f2bf(tile[threadIdx.x][ty + j]);
}

// ======================================================================
// 256x256-tile GEMM, BK=64, 8 waves (2M x 4N, wave-tile 128x64).
// Quadrant phases with kk-SPLIT MFMA: reads ordered kk0-cluster then
// kk1-cluster; MFMA runs all-kk0 then all-kk1, so the compiler's
// fine-grained lgkmcnt waits overlap kk1 LDS delivery under kk0 MFMA
// (zero extra registers). Stage-early/gate-late: p1 stages A-hi+B-hi
// (u+1), p2 B-lo(u+1), p4 stages A-lo(u+2) AFTER p3's barrier (fixes
// same-buffer write-vs-read race) then gates vmcnt(2) -> every staged
// half has >=2 phases of HBM latency slack; only A-lo(u+2) stays in
// flight across the gate (T4).
// MODE 0 (GEMM1): h_all[row, e*F+col] = bf16(gate*relu(x@W1_e + b1))
// MODE 1 (GEMM2): part[z] = A'(BT,KCAT) x B'^T  (K-split z, f32)
// ======================================================================
template <int MODE>
__global__ __launch_bounds__(512, 2) void gemm256(
    const u16* __restrict__ A0, const u16* __restrict__ B0,
    const float* __restrict__ bias, const float* __restrict__ gate,
    u16* __restrict__ hout, float* __restrict__ part) {
  // LDS bytes: A[p][row][gran]: p*32768 + row*128 + gran*16   (0..65535)
  //            B[p][row][gran]: 65536 + p*32768 + row*128 + gran*16
  __shared__ u16 lds[65536];   // 128 KiB

  constexpr int NXT  = (MODE == 0 ? 16 : 4);
  constexpr int NYT  = 16;
  constexpr int NZ   = (MODE == 0 ? 8 : 4);
  constexpr int NT   = (MODE == 0 ? HDIM / 64 : (KCAT / NZ) / 64);  // 16 / 128
  constexpr size_t Kstr = (MODE == 0 ? (size_t)HDIM : (size_t)KCAT);

  const int tid  = threadIdx.x;
  const int wid  = tid >> 6;
  const int lane = tid & 63;

  int lin = (blockIdx.z * gridDim.y + blockIdx.y) * gridDim.x + blockIdx.x;
  lin = xcd_swizzle(lin, NXT * NYT * NZ);
  const int bn = lin % NXT; lin /= NXT;
  const int bm = lin % NYT; lin /= NYT;
  const int bz = lin;                       // expert (MODE0) or k-split (MODE1)

  const u16* Abase = A0 + (size_t)bm * 256 * Kstr
                        + (MODE == 0 ? 0 : (size_t)bz * (KCAT / NZ));
  const u16* Bbase = (MODE == 0 ? B0 + (size_t)bz * FDIM * HDIM
                                : B0 + (size_t)bz * (KCAT / NZ))
                        + (size_t)bn * 256 * Kstr;

  // ---- staging geometry (hoisted): thread covers (row=tid>>3 [+64], granule=tid&7)
  const int srow = tid >> 3;                         // 0..63
  const int sg   = tid & 7;                          // dest granule
  const int scol = (sg ^ (srow & 7)) * 8;            // pre-swizzled src col (u16)
  const u16* gA = Abase + (size_t)srow * Kstr + scol;   // A-lo row base
  const u16* gB = Bbase + (size_t)srow * Kstr + scol;   // B-lo row base
  char* const ldsT = (char*)lds + tid * 16;

  // STAGEH(T, WH): stage half-tile WH (0=A-lo,1=A-hi,2=B-lo,3=B-hi) of K-tile T
  #define STAGEH(T, WH) do {                                              \
    const u16* _s = ((WH) < 2 ? gA : gB)                                  \
                    + (size_t)(((WH) & 1) * 128) * Kstr + (size_t)(T) * 64;\
    char* _d = ldsT + ((WH) >= 2 ? 65536 : 0) + ((T) & 1) * 32768         \
               + ((WH) & 1) * 16384;                                      \
    gload_lds16(_s, _d);                                                  \
    gload_lds16(_s + 64 * Kstr, _d + 8192);                               \
  } while (0)

  const int wm = wid >> 2, wn = wid & 3;   // 2M x 4N waves, each 128x64
  const int l4 = lane >> 4, l15 = lane & 15;

  f32x4 acc[8][4];
  #pragma unroll
  for (int i = 0; i < 8; ++i)
    #pragma unroll
    for (int j = 0; j < 4; ++j) acc[i][j] = {0.f, 0.f, 0.f, 0.f};

  // swizzled LDS read byte-offsets (kk0; kk1 = ^64 since granule^4 -> byte^0x40)
  int aof[8], bof[4];
  #pragma unroll
  for (int mi = 0; mi < 8; ++mi) {
    int row = wm * 128 + mi * 16 + l15;
    aof[mi] = row * 128 + ((l4 ^ (row & 7)) * 16);
  }
  #pragma unroll
  for (int ni = 0; ni < 4; ++ni) {
    int row = wn * 64 + ni * 16 + l15;
    bof[ni] = 65536 + row * 128 + ((l4 ^ (row & 7)) * 16);
  }

  #define LD(off) (*(const short8*)((const char*)lds + (off)))

  short8 a_[8][2], b_[4][2];

  // 8-MFMA quadrant-half: mi in [M0,M0+4) x ni in {N0,N0+1} at one kk
  #define QUADK(M0, N0, KK) do {                                          \
    __builtin_amdgcn_s_setprio(1);                                        \
    _Pragma("unroll")                                                     \
    for (int i = 0; i < 4; ++i) {                                         \
      acc[(M0) + i][N0]     = __builtin_amdgcn_mfma_f32_16x16x32_bf16(    \
          a_[(M0) + i][KK], b_[N0][KK],     acc[(M0) + i][N0],     0, 0, 0);\
      acc[(M0) + i][(N0)+1] = __builtin_amdgcn_mfma_f32_16x16x32_bf16(    \
          a_[(M0) + i][KK], b_[(N0)+1][KK], acc[(M0) + i][(N0)+1], 0, 0, 0);\
    }                                                                     \
    __builtin_amdgcn_s_setprio(0);                                        \
  } while (0)

  // ---- prologue: tile 0 fully + A-lo(1); gate all of tile 0 ----
  STAGEH(0, 0); STAGEH(0, 1); STAGEH(0, 2); STAGEH(0, 3);
  STAGEH(1, 0);
  VMWAIT2();    // 10 outstanding -> <=2: tile 0 landed (A-lo(1) in flight)
  BAR();

  for (int u = 0; u < NT; ++u) {
    const int pP = (u & 1) * 32768;

    // -- p1: reads a03+b01 (kk0 cluster, then kk1); stage A-hi,B-hi(u+1) --
    a_[0][0] = LD(pP + aof[0]); a_[1][0] = LD(pP + aof[1]);
    a_[2][0] = LD(pP + aof[2]); a_[3][0] = LD(pP + aof[3]);
    b_[0][0] = LD(pP + bof[0]); b_[1][0] = LD(pP + bof[1]);
    a_[0][1] = LD(pP + (aof[0] ^ 64)); a_[1][1] = LD(pP + (aof[1] ^ 64));
    a_[2][1] = LD(pP + (aof[2] ^ 64)); a_[3][1] = LD(pP + (aof[3] ^ 64));
    b_[0][1] = LD(pP + (bof[0] ^ 64)); b_[1][1] = LD(pP + (bof[1] ^ 64));
    if (u + 1 < NT) { STAGEH(u + 1, 1); STAGEH(u + 1, 3); }
    BAR();
    QUADK(0, 0, 0);
    QUADK(0, 0, 1);
    BAR();

    // -- p2: reads b23 (kk0, kk1); stage B-lo(u+1) --
    b_[2][0] = LD(pP + bof[2]); b_[3][0] = LD(pP + bof[3]);
    b_[2][1] = LD(pP + (bof[2] ^ 64)); b_[3][1] = LD(pP + (bof[3] ^ 64));
    if (u + 1 < NT) STAGEH(u + 1, 2);
    BAR();
    QUADK(0, 2, 0);
    QUADK(0, 2, 1);
    BAR();

    // -- p3: reads a47 (kk0, kk1) --
    a_[4][0] = LD(pP + aof[4]); a_[5][0] = LD(pP + aof[5]);
    a_[6][0] = LD(pP + aof[6]); a_[7][0] = LD(pP + aof[7]);
    a_[4][1] = LD(pP + (aof[4] ^ 64)); a_[5][1] = LD(pP + (aof[5] ^ 64));
    a_[6][1] = LD(pP + (aof[6] ^ 64)); a_[7][1] = LD(pP + (aof[7] ^ 64));
    BAR();
    QUADK(4, 0, 0);
    QUADK(4, 0, 1);
    BAR();

    // -- p4: stage A-lo(u+2) (post-p3-barrier: no write-vs-read race);
    //        counted gate; publish; MFMA Q4 --
    if (u + 2 < NT) STAGEH(u + 2, 0);
    if (u + 2 < NT) { VMWAIT2(); } else if (u + 1 < NT) { VMWAIT0(); }
    BAR();
    QUADK(4, 2, 0);
    QUADK(4, 2, 1);
    // no trailing barrier: next phase's stage targets were last read at
    // p3 (consumed in-phase) and are >=2 barriers away; next reads are
    // gated by the BAR above.
  }

  // ---------------- epilogue ----------------
  const int rowbase = bm * 256 + wm * 128;
  const int colbase = bn * 256 + wn * 64;

  if constexpr (MODE == 0) {
    float bv[4];
    #pragma unroll
    for (int ni = 0; ni < 4; ++ni)
      bv[ni] = bias[(size_t)bz * FDIM + colbase + ni * 16 + l15];
    #pragma unroll
    for (int mi = 0; mi < 8; ++mi) {
      #pragma unroll
      for (int r = 0; r < 4; ++r) {
        const int row = rowbase + mi * 16 + l4 * 4 + r;
        const float gv = gate[(size_t)row * 8 + bz];
        #pragma unroll
        for (int ni = 0; ni < 4; ++ni) {
          const int col = colbase + ni * 16 + l15;
          float v = fmaxf(acc[mi][ni][r] + bv[ni], 0.f);
          hout[(size_t)row * KCAT + (size_t)bz * FDIM + col] = f2bf(gv * v);
        }
      }
    }
  } else {
    float* pp = part + (size_t)bz * BT * HDIM;
    #pragma unroll
    for (int mi = 0; mi < 8; ++mi) {
      #pragma unroll
      for (int r = 0; r < 4; ++r) {
        const int row = rowbase + mi * 16 + l4 * 4 + r;
        #pragma unroll
        for (int ni = 0; ni < 4; ++ni) {
          const int col = colbase + ni * 16 + l15;
          pp[(size_t)row * HDIM + col] = acc[mi][ni][r];
        }
      }
    }
  }
  #undef STAGEH
  #undef LD
  #undef QUADK
}

// ---------- reduce: out = sum_z part[z] + sum_e gate[row][e]*b2[e][col] ----------
__global__ __launch_bounds__(256) void reduce_kernel(
    const float* __restrict__ part, const float* __restrict__ gate,
    const float* __restrict__ b2, float* __restrict__ out) {
  const int i = (blockIdx.x * 256 + threadIdx.x) * 4;
  const int row = i >> 10, col = i & 1023;
  float4 s = *(const float4*)(part + i);
  #pragma unroll
  for (int z = 1; z < 4; ++z) {
    float4 t = *(const float4*)(part + (size_t)z * BT * HDIM + i);
    s.x += t.x; s.y += t.y; s.z += t.z; s.w += t.w;
  }
  const float* g = gate + (size_t)row * 8;
  #pragma unroll
  for (int e = 0; e < 8; ++e) {
    float ge = g[e];
    float4 bv = *(const float4*)(b2 + (size_t)e * HDIM + col);
    s.x += ge * bv.x; s.y += ge * bv.y; s.z += ge * bv.z; s.w += ge * bv.w;
  }
  *(float4*)(out + i) = s;
}

// ======================================================================
// Fallback (R2-proven): 128x128-tile per-expert GEMMs, used if ws too small
// ======================================================================
template <int Ndim, int Kdim, int EPI>
__global__ __launch_bounds__(256) void gemm_fb(
    const u16* __restrict__ A, const u16* __restrict__ Bt,
    const float* __restrict__ bias, const float* __restrict__ gate,
    int expert, u16* __restrict__ Hout, float* __restrict__ Cout) {
  __shared__ u16 Atile[128 * 32];
  __shared__ u16 Btile[128 * 32];
  const int tid  = threadIdx.x;
  const int wid  = tid >> 6;
  const int lane = tid & 63;
  const int NXT = Ndim / 128;
  const int nwg = gridDim.x * gridDim.y;
  const int bid = xcd_swizzle(blockIdx.y * gridDim.x + blockIdx.x, nwg);
  const int bn = bid % NXT, bm = bid / NXT;
  const int wm = wid >> 1, wn = wid & 1;
  const int l4  = lane >> 4, l15 = lane & 15;
  f32x4 acc[4][4];
  #pragma unroll
  for (int i = 0; i < 4; ++i)
    #pragma unroll
    for (int j = 0; j < 4; ++j) acc[i][j] = {0.f, 0.f, 0.f, 0.f};
  const int srow = lane >> 2;
  const int scol = (lane & 3) * 8;
  for (int k0 = 0; k0 < Kdim; k0 += 32) {
    __syncthreads();
    #pragma unroll
    for (int i = 0; i < 2; ++i) {
      int c = wid * 2 + i;
      gload_lds16(A  + (size_t)(bm * 128 + c * 16 + srow) * Kdim + k0 + scol, &Atile[c * 512]);
      gload_lds16(Bt + (size_t)(bn * 128 + c * 16 + srow) * Kdim + k0 + scol, &Btile[c * 512]);
    }
    __syncthreads();
    short8 af[4], bf[4];
    #pragma unroll
    for (int mi = 0; mi < 4; ++mi)
      af[mi] = *(const short8*)&Atile[(wm * 64 + mi * 16 + l15) * 32 + l4 * 8];
    #pragma unroll
    for (int ni = 0; ni < 4; ++ni)
      bf[ni] = *(const short8*)&Btile[(wn * 64 + ni * 16 + l15) * 32 + l4 * 8];
    #pragma unroll
    for (int mi = 0; mi < 4; ++mi)
      #pragma unroll
      for (int ni = 0; ni < 4; ++ni)
        acc[mi][ni] = __builtin_amdgcn_mfma_f32_16x16x32_bf16(af[mi], bf[ni], acc[mi][ni], 0, 0, 0);
  }
  const int cm0 = bm * 128 + wm * 64;
  const int cn0 = bn * 128 + wn * 64;
  float bv[4];
  #pragma unroll
  for (int ni = 0; ni < 4; ++ni) bv[ni] = bias[cn0 + ni * 16 + l15];
  #pragma unroll
  for (int mi = 0; mi < 4; ++mi) {
    #pragma unroll
    for (int r = 0; r < 4; ++r) {
      const int row = cm0 + mi * 16 + l4 * 4 + r;
      float gv = 0.f;
      if (EPI != 0) gv = gate[(size_t)row * 8 + expert];
      #pragma unroll
      for (int ni = 0; ni < 4; ++ni) {
        const int col = cn0 + ni * 16 + l15;
        float v = acc[mi][ni][r] + bv[ni];
        if (EPI == 0)      Hout[(size_t)row * Ndim + col] = f2bf(fmaxf(v, 0.f));
        else if (EPI == 1) Cout[(size_t)row * Ndim + col] = gv * v;
        else               Cout[(size_t)row * Ndim + col] += gv * v;
      }
    }
  }
}

// ---------- launch ----------
extern "C" void kernel_launch(void* const* d_in, const int* in_sizes, int n_in,
                              void* d_out, int out_size, void* d_ws, size_t ws_size,
                              hipStream_t stream) {
  const float* x  = (const float*)d_in[0];
  const float* Wr = (const float*)d_in[1];
  const float* br = (const float*)d_in[2];
  const float* W1 = (const float*)d_in[3];
  const float* b1 = (const float*)d_in[4];
  const float* W2 = (const float*)d_in[5];
  const float* b2 = (const float*)d_in[6];
  float* out = (float*)d_out;

  const size_t sz_gate = (size_t)BT * EDIM * 4;            // 128 KB
  const size_t sz_xb   = (size_t)BT * HDIM * 2;            // 8 MB
  const size_t sz_w1t  = (size_t)EDIM * FDIM * HDIM * 2;   // 64 MB
  const size_t sz_w2t  = (size_t)EDIM * HDIM * FDIM * 2;   // 64 MB
  const size_t sz_hall = (size_t)BT * KCAT * 2;            // 256 MB
  const size_t need_primary = sz_gate + sz_xb + sz_w1t + sz_w2t + sz_hall;

  char* p = (char*)d_ws;
  float* gate = (float*)p; p += sz_gate;
  u16* xb   = (u16*)p;     p += sz_xb;
  u16* w1t  = (u16*)p;     char* w1t_region = (char*)w1t; p += sz_w1t;
  u16* w2t  = (u16*)p;     p += sz_w2t;

  router_kernel<<<BT / 4, 256, 0, stream>>>(x, Wr, br, gate);
  cast_x_kernel<<<(BT * HDIM) / (256 * 8), 256, 0, stream>>>(x, xb);
  // W1 (E,H,F) -> w1t[e][f][h]  (rstride=H, estride=F*H)
  transpose_cast_kernel<<<dim3(FDIM / 32, HDIM / 32, EDIM), dim3(32, 8), 0, stream>>>(
      W1, w1t, HDIM, FDIM, HDIM, (size_t)FDIM * HDIM);

  if (ws_size >= need_primary) {
    u16* h_all = (u16*)p;                       // (BT, KCAT) bf16
    float* part = (float*)w1t_region;           // 4 x (BT,H) f32, aliases w1t after G1
    // W2 (E,F,H) -> B'[n][e*F+f]  (rstride=KCAT, estride=F)
    transpose_cast_kernel<<<dim3(HDIM / 32, FDIM / 32, EDIM), dim3(32, 8), 0, stream>>>(
        W2, w2t, FDIM, HDIM, KCAT, FDIM);
    // GEMM1: all experts, h_all[row, e*F+col] = bf16(gate*relu(x@W1_e + b1_e))
    gemm256<0><<<dim3(16, 16, 8), 512, 0, stream>>>(xb, w1t, b1, gate, h_all, nullptr);
    // GEMM2: (g.h) @ concat(W2), split-K x4 -> part
    gemm256<1><<<dim3(4, 16, 4), 512, 0, stream>>>(h_all, w2t, nullptr, nullptr, nullptr, part);
    // out = sum_z part + sum_e g_e * b2_e
    reduce_kernel<<<(BT * HDIM) / (256 * 4), 256, 0, stream>>>(part, gate, b2, out);
  } else {
    // -------- fallback: R2-proven path --------
    u16* h = (u16*)p;   // (BT, F) one expert, 32 MB
    transpose_cast_kernel<<<dim3(HDIM / 32, FDIM / 32, EDIM), dim3(32, 8), 0, stream>>>(
        W2, w2t, FDIM, HDIM, FDIM, (size_t)HDIM * FDIM);
    for (int e = 0; e < EDIM; ++e) {
      gemm_fb<FDIM, HDIM, 0><<<dim3(FDIM / 128, BT / 128), 256, 0, stream>>>(
          xb, w1t + (size_t)e * FDIM * HDIM, b1 + (size_t)e * FDIM, nullptr, 0, h, nullptr);
      if (e == 0)
        gemm_fb<HDIM, FDIM, 1><<<dim3(HDIM / 128, BT / 128), 256, 0, stream>>>(
            h, w2t + (size_t)e * HDIM * FDIM, b2 + (size_t)e * HDIM, gate, e, nullptr, out);
      else
        gemm_fb<HDIM, FDIM, 2><<<dim3(HDIM / 128, BT / 128), 256, 0, stream>>>(
            h, w2t + (size_t)e * HDIM * FDIM, b2 + (size_t)e * HDIM, gate, e, nullptr, out);
    }
  }
}

// Round 11
// 622.777 us; speedup vs baseline: 1.2413x; 1.0464x over previous
//
#include <hip/hip_runtime.h>
#include <hip/hip_bf16.h>
#include <stdint.h>

// Problem dims (B=2, T=2048, H=1024, F=4096, E=8)
#define BT   4096
#define HDIM 1024
#define FDIM 4096
#define EDIM 8
#define TOPP 0.8f
#define KCAT (EDIM * FDIM)   // 32768 concatenated K for GEMM2

typedef unsigned short u16;
typedef __attribute__((ext_vector_type(8))) short  short8;
typedef __attribute__((ext_vector_type(8))) unsigned short ushort8;
typedef __attribute__((ext_vector_type(4))) float  f32x4;

// ---------- helpers ----------
__device__ __forceinline__ u16 f2bf(float f) {
  uint32_t u = __builtin_bit_cast(uint32_t, f);
  uint32_t r = u + 0x7FFFu + ((u >> 16) & 1u);   // RNE
  return (u16)(r >> 16);
}

__device__ __forceinline__ void gload_lds16(const void* g, void* l) {
  __builtin_amdgcn_global_load_lds(
      (const __attribute__((address_space(1))) uint32_t*)g,
      (__attribute__((address_space(3))) uint32_t*)l, 16, 0, 0);
}

#define VMWAIT2() asm volatile("s_waitcnt vmcnt(2)" ::: "memory")
#define VMWAIT0() asm volatile("s_waitcnt vmcnt(0)" ::: "memory")
#define BAR()     asm volatile("s_barrier" ::: "memory")
#define SB()      __builtin_amdgcn_sched_barrier(0)

// Bijective XCD-aware swizzle (m204)
__device__ __forceinline__ int xcd_swizzle(int bid, int nwg) {
  const int nx = 8;
  int q = nwg / nx, r = nwg % nx;
  int xcd = bid % nx, lin = bid / nx;
  int base = (xcd < r) ? xcd * (q + 1) : r * (q + 1) + (xcd - r) * q;
  return base + lin;
}

// ---------- router: probs -> top-p gate (stable argsort semantics) ----------
__global__ __launch_bounds__(256) void router_kernel(
    const float* __restrict__ x, const float* __restrict__ Wr,
    const float* __restrict__ br, float* __restrict__ gate) {
  const int wid  = threadIdx.x >> 6;
  const int lane = threadIdx.x & 63;
  const int token = blockIdx.x * 4 + wid;
  const float* xr = x + (size_t)token * HDIM;

  float p[8] = {0.f,0.f,0.f,0.f,0.f,0.f,0.f,0.f};
  #pragma unroll
  for (int j = 0; j < 16; ++j) {
    int hh = lane * 16 + j;
    float xv = xr[hh];
    const float* wrow = Wr + (size_t)hh * 8;
    #pragma unroll
    for (int e = 0; e < 8; ++e) p[e] += xv * wrow[e];
  }
  #pragma unroll
  for (int off = 32; off > 0; off >>= 1) {
    #pragma unroll
    for (int e = 0; e < 8; ++e) p[e] += __shfl_xor(p[e], off, 64);
  }
  float mx = -1e30f;
  #pragma unroll
  for (int e = 0; e < 8; ++e) { p[e] += br[e]; mx = fmaxf(mx, p[e]); }
  float s = 0.f;
  #pragma unroll
  for (int e = 0; e < 8; ++e) { p[e] = expf(p[e] - mx); s += p[e]; }
  float inv = 1.0f / s;
  #pragma unroll
  for (int e = 0; e < 8; ++e) p[e] *= inv;

  if (lane == 0) {
    float g[8];
    #pragma unroll
    for (int e = 0; e < 8; ++e) {
      float pe = p[e];
      float cum = pe; int rank = 0;
      #pragma unroll
      for (int e2 = 0; e2 < 8; ++e2) {
        if (e2 == e) continue;
        bool before = (p[e2] > pe) || (p[e2] == pe && e2 < e);
        if (before) { cum += p[e2]; rank++; }
      }
      bool keep = (cum < TOPP) || (rank == 0);
      g[e] = keep ? pe : 0.f;
    }
    float* gp = gate + (size_t)token * 8;
    #pragma unroll
    for (int e = 0; e < 8; ++e) gp[e] = g[e];
  }
}

// ---------- cast x f32 -> bf16 ----------
__global__ __launch_bounds__(256) void cast_x_kernel(
    const float* __restrict__ in, u16* __restrict__ out) {
  int i = (blockIdx.x * 256 + threadIdx.x) * 8;
  float4 a = *(const float4*)(in + i);
  float4 b = *(const float4*)(in + i + 4);
  ushort8 o;
  o[0] = f2bf(a.x); o[1] = f2bf(a.y); o[2] = f2bf(a.z); o[3] = f2bf(a.w);
  o[4] = f2bf(b.x); o[5] = f2bf(b.y); o[6] = f2bf(b.z); o[7] = f2bf(b.w);
  *(ushort8*)(out + i) = o;
}

// ---------- transpose + cast: per-expert (R,C) f32 -> out[e*estride + c*rstride + r] bf16
__global__ __launch_bounds__(256) void transpose_cast_kernel(
    const float* __restrict__ in, u16* __restrict__ out, int R, int C,
    size_t rstride, size_t estride) {
  __shared__ float tile[32][33];
  const int e = blockIdx.z;
  const float* ip = in + (size_t)e * R * C;
  u16* op = out + (size_t)e * estride;
  int x  = blockIdx.x * 32 + threadIdx.x;   // C coord
  int y0 = blockIdx.y * 32;                 // R tile base
  int ty = threadIdx.y;                     // 0..7
  #pragma unroll
  for (int j = 0; j < 32; j += 8)
    tile[ty + j][threadIdx.x] = ip[(size_t)(y0 + ty + j) * C + x];
  __syncthreads();
  int xo  = y0 + threadIdx.x;               // R coord (contiguous on out)
  int yo0 = blockIdx.x * 32;
  #pragma unroll
  for (int j = 0; j < 32; j += 8)
    op[(size_t)(yo0 + ty + j) * rstride + xo] = f2bf(tile[threadIdx.x][ty + j]);
}

// ======================================================================
// 256x256-tile GEMM, BK=64, 8 waves (2M x 4N, wave-tile 128x64).
// TWO barriers per K-tile: {deep-stage A-lo(u+1); gate vmcnt(2); BAR;
// kk0: 12 reads + stage(1,3) + 32 MFMA; [SB cap]; kk1: 12 reads +
// stage(2) + 32 MFMA; BAR}. Between the two BARs waves desync -> one
// wave's MFMA overlaps another's ds_read/stage (m114 cross-wave
// overlap), which the previous 7-barrier lockstep suppressed.
// Race ledger (all PROVEN, no timing assumptions):
//  - stage(u+1,{1,3,2}) write pN: last readers are iter u-1's reads,
//    serviced before u-1's MFMAs which precede u-1's closing BAR.
//  - deep stage(u+1,0) writes pN A-lo at iter-u start: after u-1's
//    closing BAR, same proof.
//  - gate vmcnt(2): FIFO => 2 newest = just-issued A-lo(u+1) pair;
//    everything older (all of tile u) must have landed. Tail u=NT-1
//    uses vmcnt(0) (no new issue => count-2 would leave tile-u loads).
//  - pP's kk1 reads are consumed by MFMAs before the closing BAR,
//    which precedes the next iter's A-lo(u+2)->pP stage.
// MODE 0 (GEMM1): h_all[row, e*F+col] = bf16(gate*relu(x@W1_e + b1))
// MODE 1 (GEMM2): part[z] = A'(BT,KCAT) x B'^T  (K-split z, f32)
// ======================================================================
template <int MODE>
__global__ __launch_bounds__(512, 2) void gemm256(
    const u16* __restrict__ A0, const u16* __restrict__ B0,
    const float* __restrict__ bias, const float* __restrict__ gate,
    u16* __restrict__ hout, float* __restrict__ part) {
  // LDS bytes: A[p][row][gran]: p*32768 + row*128 + gran*16   (0..65535)
  //            B[p][row][gran]: 65536 + p*32768 + row*128 + gran*16
  __shared__ u16 lds[65536];   // 128 KiB

  constexpr int NXT  = (MODE == 0 ? 16 : 4);
  constexpr int NYT  = 16;
  constexpr int NZ   = (MODE == 0 ? 8 : 4);
  constexpr int NT   = (MODE == 0 ? HDIM / 64 : (KCAT / NZ) / 64);  // 16 / 128
  constexpr size_t Kstr = (MODE == 0 ? (size_t)HDIM : (size_t)KCAT);

  const int tid  = threadIdx.x;
  const int wid  = tid >> 6;
  const int lane = tid & 63;

  int lin = (blockIdx.z * gridDim.y + blockIdx.y) * gridDim.x + blockIdx.x;
  lin = xcd_swizzle(lin, NXT * NYT * NZ);
  const int bn = lin % NXT; lin /= NXT;
  const int bm = lin % NYT; lin /= NYT;
  const int bz = lin;                       // expert (MODE0) or k-split (MODE1)

  const u16* Abase = A0 + (size_t)bm * 256 * Kstr
                        + (MODE == 0 ? 0 : (size_t)bz * (KCAT / NZ));
  const u16* Bbase = (MODE == 0 ? B0 + (size_t)bz * FDIM * HDIM
                                : B0 + (size_t)bz * (KCAT / NZ))
                        + (size_t)bn * 256 * Kstr;

  // ---- staging geometry (hoisted): thread covers (row=tid>>3 [+64], granule=tid&7)
  const int srow = tid >> 3;                         // 0..63
  const int sg   = tid & 7;                          // dest granule
  const int scol = (sg ^ (srow & 7)) * 8;            // pre-swizzled src col (u16)
  const u16* gA = Abase + (size_t)srow * Kstr + scol;   // A-lo row base
  const u16* gB = Bbase + (size_t)srow * Kstr + scol;   // B-lo row base
  char* const ldsT = (char*)lds + tid * 16;

  // STAGEH(T, WH): stage half-tile WH (0=A-lo,1=A-hi,2=B-lo,3=B-hi) of K-tile T
  #define STAGEH(T, WH) do {                                              \
    const u16* _s = ((WH) < 2 ? gA : gB)                                  \
                    + (size_t)(((WH) & 1) * 128) * Kstr + (size_t)(T) * 64;\
    char* _d = ldsT + ((WH) >= 2 ? 65536 : 0) + ((T) & 1) * 32768         \
               + ((WH) & 1) * 16384;                                      \
    gload_lds16(_s, _d);                                                  \
    gload_lds16(_s + 64 * Kstr, _d + 8192);                               \
  } while (0)

  const int wm = wid >> 2, wn = wid & 3;   // 2M x 4N waves, each 128x64
  const int l4 = lane >> 4, l15 = lane & 15;

  f32x4 acc[8][4];
  #pragma unroll
  for (int i = 0; i < 8; ++i)
    #pragma unroll
    for (int j = 0; j < 4; ++j) acc[i][j] = {0.f, 0.f, 0.f, 0.f};

  // swizzled LDS read byte-offsets (kk0; kk1 = ^64 since granule^4 -> byte^0x40)
  int aof[8], bof[4];
  #pragma unroll
  for (int mi = 0; mi < 8; ++mi) {
    int row = wm * 128 + mi * 16 + l15;
    aof[mi] = row * 128 + ((l4 ^ (row & 7)) * 16);
  }
  #pragma unroll
  for (int ni = 0; ni < 4; ++ni) {
    int row = wn * 64 + ni * 16 + l15;
    bof[ni] = 65536 + row * 128 + ((l4 ^ (row & 7)) * 16);
  }

  #define LD(off) (*(const short8*)((const char*)lds + (off)))

  short8 a_[8], b_[4];

  // 8-MFMA quadrant-half: mi in [M0,M0+4) x ni in {N0,N0+1} (current frags)
  #define QUADK(M0, N0) do {                                              \
    __builtin_amdgcn_s_setprio(1);                                        \
    _Pragma("unroll")                                                     \
    for (int i = 0; i < 4; ++i) {                                         \
      acc[(M0) + i][N0]     = __builtin_amdgcn_mfma_f32_16x16x32_bf16(    \
          a_[(M0) + i], b_[N0],     acc[(M0) + i][N0],     0, 0, 0);      \
      acc[(M0) + i][(N0)+1] = __builtin_amdgcn_mfma_f32_16x16x32_bf16(    \
          a_[(M0) + i], b_[(N0)+1], acc[(M0) + i][(N0)+1], 0, 0, 0);      \
    }                                                                     \
    __builtin_amdgcn_s_setprio(0);                                        \
  } while (0)

  // read the 12 fragments of one kk half (XB = 0 or 64 byte XOR)
  #define RD12(P, XB) do {                                                \
    a_[0] = LD((P) + (aof[0] ^ (XB))); a_[1] = LD((P) + (aof[1] ^ (XB))); \
    a_[2] = LD((P) + (aof[2] ^ (XB))); a_[3] = LD((P) + (aof[3] ^ (XB))); \
    b_[0] = LD((P) + (bof[0] ^ (XB))); b_[1] = LD((P) + (bof[1] ^ (XB))); \
    b_[2] = LD((P) + (bof[2] ^ (XB))); b_[3] = LD((P) + (bof[3] ^ (XB))); \
    a_[4] = LD((P) + (aof[4] ^ (XB))); a_[5] = LD((P) + (aof[5] ^ (XB))); \
    a_[6] = LD((P) + (aof[6] ^ (XB))); a_[7] = LD((P) + (aof[7] ^ (XB))); \
  } while (0)

  // ---- prologue: stage tile 0 fully (8 loads) ----
  STAGEH(0, 0); STAGEH(0, 1); STAGEH(0, 2); STAGEH(0, 3);

  for (int u = 0; u < NT; ++u) {
    const int pP = (u & 1) * 32768;

    // deep-stage A-lo(u+1), then gate: 2 newest in FIFO = that pair,
    // everything older (all of tile u) must have landed.
    if (u + 1 < NT) { STAGEH(u + 1, 0); VMWAIT2(); } else { VMWAIT0(); }
    BAR();   // publish tile u

    // ---- kk0 half: 12 reads + stage(1,3) + 32 MFMA ----
    RD12(pP, 0);
    if (u + 1 < NT) { STAGEH(u + 1, 1); STAGEH(u + 1, 3); }
    QUADK(0, 0); QUADK(0, 2); QUADK(4, 0); QUADK(4, 2);

    SB();   // cap register pressure: kk1 reads may not hoist above kk0 MFMAs

    // ---- kk1 half: 12 reads + stage(2) + 32 MFMA ----
    RD12(pP, 64);
    if (u + 1 < NT) STAGEH(u + 1, 2);
    QUADK(0, 0); QUADK(0, 2); QUADK(4, 0); QUADK(4, 2);

    BAR();   // close: kk1 reads consumed; enables next iter's A-lo stage into pP
  }

  // ---------------- epilogue ----------------
  const int rowbase = bm * 256 + wm * 128;
  const int colbase = bn * 256 + wn * 64;

  if constexpr (MODE == 0) {
    float bv[4];
    #pragma unroll
    for (int ni = 0; ni < 4; ++ni)
      bv[ni] = bias[(size_t)bz * FDIM + colbase + ni * 16 + l15];
    #pragma unroll
    for (int mi = 0; mi < 8; ++mi) {
      #pragma unroll
      for (int r = 0; r < 4; ++r) {
        const int row = rowbase + mi * 16 + l4 * 4 + r;
        const float gv = gate[(size_t)row * 8 + bz];
        #pragma unroll
        for (int ni = 0; ni < 4; ++ni) {
          const int col = colbase + ni * 16 + l15;
          float v = fmaxf(acc[mi][ni][r] + bv[ni], 0.f);
          hout[(size_t)row * KCAT + (size_t)bz * FDIM + col] = f2bf(gv * v);
        }
      }
    }
  } else {
    float* pp = part + (size_t)bz * BT * HDIM;
    #pragma unroll
    for (int mi = 0; mi < 8; ++mi) {
      #pragma unroll
      for (int r = 0; r < 4; ++r) {
        const int row = rowbase + mi * 16 + l4 * 4 + r;
        #pragma unroll
        for (int ni = 0; ni < 4; ++ni) {
          const int col = colbase + ni * 16 + l15;
          pp[(size_t)row * HDIM + col] = acc[mi][ni][r];
        }
      }
    }
  }
  #undef STAGEH
  #undef LD
  #undef QUADK
  #undef RD12
}

// ---------- reduce: out = sum_z part[z] + sum_e gate[row][e]*b2[e][col] ----------
__global__ __launch_bounds__(256) void reduce_kernel(
    const float* __restrict__ part, const float* __restrict__ gate,
    const float* __restrict__ b2, float* __restrict__ out) {
  const int i = (blockIdx.x * 256 + threadIdx.x) * 4;
  const int row = i >> 10, col = i & 1023;
  float4 s = *(const float4*)(part + i);
  #pragma unroll
  for (int z = 1; z < 4; ++z) {
    float4 t = *(const float4*)(part + (size_t)z * BT * HDIM + i);
    s.x += t.x; s.y += t.y; s.z += t.z; s.w += t.w;
  }
  const float* g = gate + (size_t)row * 8;
  #pragma unroll
  for (int e = 0; e < 8; ++e) {
    float ge = g[e];
    float4 bv = *(const float4*)(b2 + (size_t)e * HDIM + col);
    s.x += ge * bv.x; s.y += ge * bv.y; s.z += ge * bv.z; s.w += ge * bv.w;
  }
  *(float4*)(out + i) = s;
}

// ======================================================================
// Fallback (R2-proven): 128x128-tile per-expert GEMMs, used if ws too small
// ======================================================================
template <int Ndim, int Kdim, int EPI>
__global__ __launch_bounds__(256) void gemm_fb(
    const u16* __restrict__ A, const u16* __restrict__ Bt,
    const float* __restrict__ bias, const float* __restrict__ gate,
    int expert, u16* __restrict__ Hout, float* __restrict__ Cout) {
  __shared__ u16 Atile[128 * 32];
  __shared__ u16 Btile[128 * 32];
  const int tid  = threadIdx.x;
  const int wid  = tid >> 6;
  const int lane = tid & 63;
  const int NXT = Ndim / 128;
  const int nwg = gridDim.x * gridDim.y;
  const int bid = xcd_swizzle(blockIdx.y * gridDim.x + blockIdx.x, nwg);
  const int bn = bid % NXT, bm = bid / NXT;
  const int wm = wid >> 1, wn = wid & 1;
  const int l4  = lane >> 4, l15 = lane & 15;
  f32x4 acc[4][4];
  #pragma unroll
  for (int i = 0; i < 4; ++i)
    #pragma unroll
    for (int j = 0; j < 4; ++j) acc[i][j] = {0.f, 0.f, 0.f, 0.f};
  const int srow = lane >> 2;
  const int scol = (lane & 3) * 8;
  for (int k0 = 0; k0 < Kdim; k0 += 32) {
    __syncthreads();
    #pragma unroll
    for (int i = 0; i < 2; ++i) {
      int c = wid * 2 + i;
      gload_lds16(A  + (size_t)(bm * 128 + c * 16 + srow) * Kdim + k0 + scol, &Atile[c * 512]);
      gload_lds16(Bt + (size_t)(bn * 128 + c * 16 + srow) * Kdim + k0 + scol, &Btile[c * 512]);
    }
    __syncthreads();
    short8 af[4], bf[4];
    #pragma unroll
    for (int mi = 0; mi < 4; ++mi)
      af[mi] = *(const short8*)&Atile[(wm * 64 + mi * 16 + l15) * 32 + l4 * 8];
    #pragma unroll
    for (int ni = 0; ni < 4; ++ni)
      bf[ni] = *(const short8*)&Btile[(wn * 64 + ni * 16 + l15) * 32 + l4 * 8];
    #pragma unroll
    for (int mi = 0; mi < 4; ++mi)
      #pragma unroll
      for (int ni = 0; ni < 4; ++ni)
        acc[mi][ni] = __builtin_amdgcn_mfma_f32_16x16x32_bf16(af[mi], bf[ni], acc[mi][ni], 0, 0, 0);
  }
  const int cm0 = bm * 128 + wm * 64;
  const int cn0 = bn * 128 + wn * 64;
  float bv[4];
  #pragma unroll
  for (int ni = 0; ni < 4; ++ni) bv[ni] = bias[cn0 + ni * 16 + l15];
  #pragma unroll
  for (int mi = 0; mi < 4; ++mi) {
    #pragma unroll
    for (int r = 0; r < 4; ++r) {
      const int row = cm0 + mi * 16 + l4 * 4 + r;
      float gv = 0.f;
      if (EPI != 0) gv = gate[(size_t)row * 8 + expert];
      #pragma unroll
      for (int ni = 0; ni < 4; ++ni) {
        const int col = cn0 + ni * 16 + l15;
        float v = acc[mi][ni][r] + bv[ni];
        if (EPI == 0)      Hout[(size_t)row * Ndim + col] = f2bf(fmaxf(v, 0.f));
        else if (EPI == 1) Cout[(size_t)row * Ndim + col] = gv * v;
        else               Cout[(size_t)row * Ndim + col] += gv * v;
      }
    }
  }
}

// ---------- launch ----------
extern "C" void kernel_launch(void* const* d_in, const int* in_sizes, int n_in,
                              void* d_out, int out_size, void* d_ws, size_t ws_size,
                              hipStream_t stream) {
  const float* x  = (const float*)d_in[0];
  const float* Wr = (const float*)d_in[1];
  const float* br = (const float*)d_in[2];
  const float* W1 = (const float*)d_in[3];
  const float* b1 = (const float*)d_in[4];
  const float* W2 = (const float*)d_in[5];
  const float* b2 = (const float*)d_in[6];
  float* out = (float*)d_out;

  const size_t sz_gate = (size_t)BT * EDIM * 4;            // 128 KB
  const size_t sz_xb   = (size_t)BT * HDIM * 2;            // 8 MB
  const size_t sz_w1t  = (size_t)EDIM * FDIM * HDIM * 2;   // 64 MB
  const size_t sz_w2t  = (size_t)EDIM * HDIM * FDIM * 2;   // 64 MB
  const size_t sz_hall = (size_t)BT * KCAT * 2;            // 256 MB
  const size_t need_primary = sz_gate + sz_xb + sz_w1t + sz_w2t + sz_hall;

  char* p = (char*)d_ws;
  float* gate = (float*)p; p += sz_gate;
  u16* xb   = (u16*)p;     p += sz_xb;
  u16* w1t  = (u16*)p;     char* w1t_region = (char*)w1t; p += sz_w1t;
  u16* w2t  = (u16*)p;     p += sz_w2t;

  router_kernel<<<BT / 4, 256, 0, stream>>>(x, Wr, br, gate);
  cast_x_kernel<<<(BT * HDIM) / (256 * 8), 256, 0, stream>>>(x, xb);
  // W1 (E,H,F) -> w1t[e][f][h]  (rstride=H, estride=F*H)
  transpose_cast_kernel<<<dim3(FDIM / 32, HDIM / 32, EDIM), dim3(32, 8), 0, stream>>>(
      W1, w1t, HDIM, FDIM, HDIM, (size_t)FDIM * HDIM);

  if (ws_size >= need_primary) {
    u16* h_all = (u16*)p;                       // (BT, KCAT) bf16
    float* part = (float*)w1t_region;           // 4 x (BT,H) f32, aliases w1t after G1
    // W2 (E,F,H) -> B'[n][e*F+f]  (rstride=KCAT, estride=F)
    transpose_cast_kernel<<<dim3(HDIM / 32, FDIM / 32, EDIM), dim3(32, 8), 0, stream>>>(
        W2, w2t, FDIM, HDIM, KCAT, FDIM);
    // GEMM1: all experts, h_all[row, e*F+col] = bf16(gate*relu(x@W1_e + b1_e))
    gemm256<0><<<dim3(16, 16, 8), 512, 0, stream>>>(xb, w1t, b1, gate, h_all, nullptr);
    // GEMM2: (g.h) @ concat(W2), split-K x4 -> part
    gemm256<1><<<dim3(4, 16, 4), 512, 0, stream>>>(h_all, w2t, nullptr, nullptr, nullptr, part);
    // out = sum_z part + sum_e g_e * b2_e
    reduce_kernel<<<(BT * HDIM) / (256 * 4), 256, 0, stream>>>(part, gate, b2, out);
  } else {
    // -------- fallback: R2-proven path --------
    u16* h = (u16*)p;   // (BT, F) one expert, 32 MB
    transpose_cast_kernel<<<dim3(HDIM / 32, FDIM / 32, EDIM), dim3(32, 8), 0, stream>>>(
        W2, w2t, FDIM, HDIM, FDIM, (size_t)HDIM * FDIM);
    for (int e = 0; e < EDIM; ++e) {
      gemm_fb<FDIM, HDIM, 0><<<dim3(FDIM / 128, BT / 128), 256, 0, stream>>>(
          xb, w1t + (size_t)e * FDIM * HDIM, b1 + (size_t)e * FDIM, nullptr, 0, h, nullptr);
      if (e == 0)
        gemm_fb<HDIM, FDIM, 1><<<dim3(HDIM / 128, BT / 128), 256, 0, stream>>>(
            h, w2t + (size_t)e * HDIM * FDIM, b2 + (size_t)e * HDIM, gate, e, nullptr, out);
      else
        gemm_fb<HDIM, FDIM, 2><<<dim3(HDIM / 128, BT / 128), 256, 0, stream>>>(
            h, w2t + (size_t)e * HDIM * FDIM, b2 + (size_t)e * HDIM, gate, e, nullptr, out);
    }
  }
}